// Round 1
// 177.514 us; speedup vs baseline: 1.6636x; 1.6636x over previous
//
#include <hip/hip_runtime.h>

#define B_ 8
#define T_ 2048
#define E_ 768
#define D_ 128
#define SCALE 0.08838834764831845f   // 1/sqrt(128)

typedef _Float16 h8 __attribute__((ext_vector_type(8)));
typedef _Float16 h4 __attribute__((ext_vector_type(4)));
typedef float f4 __attribute__((ext_vector_type(4)));

typedef __attribute__((address_space(1))) unsigned int as1_u32;
typedef __attribute__((address_space(3))) unsigned int as3_u32;

// direct global->LDS, 16B per lane; LDS dest must be wave-uniform base (HW adds lane*16)
__device__ __forceinline__ void gl_lds16(const void* g, void* l) {
    __builtin_amdgcn_global_load_lds((const as1_u32*)g, (as3_u32*)l, 16, 0, 0);
}

// =============== Kernel 0: W (fp32 [768][128] x3) -> Wh f16 [3*128][768] ===============
__global__ __launch_bounds__(256) void w_prep(
    const float* __restrict__ Wq, const float* __restrict__ Wk,
    const float* __restrict__ Wv, _Float16* __restrict__ Wh)
{
    __shared__ float tile[64][129];   // +1 pad: transpose-read bank spread
    const int y = blockIdx.x / 12, kc = blockIdx.x % 12;
    const float* W = (y == 0) ? Wq : (y == 1) ? Wk : Wv;
    const int k0 = kc * 64, t = threadIdx.x;
#pragma unroll
    for (int i = 0; i < 32; ++i) {
        const int idx = i * 256 + t;
        tile[idx >> 7][idx & 127] = W[(size_t)(k0 + (idx >> 7)) * D_ + (idx & 127)];
    }
    __syncthreads();
    const int n = t >> 1, hf = t & 1;
#pragma unroll
    for (int j = 0; j < 4; ++j) {
        const int kk = hf * 32 + j * 8;
        h8 hv;
#pragma unroll
        for (int e = 0; e < 8; ++e) hv[e] = (_Float16)tile[kk + e][n];
        *(h8*)&Wh[(size_t)(y * 128 + n) * E_ + k0 + kk] = hv;
    }
}

// =============== Kernel 1: fused QKV projection ===============
// grid = 256 (64-row m-tile per block), block = 256 (4 waves, 96 cols each).
// B tiles now come pre-converted from Wh via global_load_lds with pre-swizzled source.
__global__ __launch_bounds__(256) void qkv_fused(
    const float* __restrict__ x, const _Float16* __restrict__ Wh,
    const float* __restrict__ bq, const float* __restrict__ bk,
    const float* __restrict__ bv,
    _Float16* __restrict__ Qh, _Float16* __restrict__ Kh,
    _Float16* __restrict__ Vt)
{
    __shared__ _Float16 As[64 * 64];        // 8 KB  x-tile, XOR-swizzled
    __shared__ _Float16 Bs[384 * 64];       // 48 KB W-tiles [row=3*128][k=64], swizzled

    const int t = threadIdx.x;
    const int lane = t & 63, w = t >> 6;
    const int quad = lane >> 4, col = lane & 15;
    const int m0 = blockIdx.x * 64;

    f4 acc[4][6];
#pragma unroll
    for (int mt = 0; mt < 4; ++mt)
#pragma unroll
        for (int nt = 0; nt < 6; ++nt) acc[mt][nt] = (f4){0.f, 0.f, 0.f, 0.f};

    const int brl = lane >> 3, bc = lane & 7;   // B-stage: 8 rows/issue, 8 chunks/row

    for (int kb = 0; kb < E_; kb += 64) {
        // ---- stage x tile: 64x64 fp32 -> f16 swizzled ----
        {
            const int r = t >> 2, cb = (t & 3) * 16;
            const float* xr = &x[(size_t)(m0 + r) * E_ + kb + cb];
#pragma unroll
            for (int i = 0; i < 4; ++i) {
                const float4 v = *(const float4*)(xr + 4 * i);
                h4 hv; hv[0] = (_Float16)v.x; hv[1] = (_Float16)v.y;
                hv[2] = (_Float16)v.z; hv[3] = (_Float16)v.w;
                const int kk4 = cb + 4 * i;
                *(h4*)&As[r * 64 + (((kk4 >> 3) ^ (r & 7)) << 3) + (kk4 & 7)] = hv;
            }
        }
        // ---- stage 3 W tiles: direct global->LDS, source pre-swizzled ----
#pragma unroll
        for (int i = 0; i < 12; ++i) {
            const int R = w * 96 + i * 8;          // wave-uniform LDS row base
            const int r = R + brl;
            gl_lds16(Wh + (size_t)r * E_ + kb + 8 * (bc ^ (r & 7)), &Bs[R * 64]);
        }
        __syncthreads();   // drains vmcnt+lgkm (single-buffered)

#pragma unroll
        for (int ks = 0; ks < 2; ++ks) {
            const int sc = ((ks << 2) + quad) ^ (col & 7);
            h8 a[4], bf[6];
#pragma unroll
            for (int mt = 0; mt < 4; ++mt)
                a[mt] = *(const h8*)&As[(mt * 16 + col) * 64 + (sc << 3)];
#pragma unroll
            for (int nt = 0; nt < 6; ++nt)
                bf[nt] = *(const h8*)&Bs[(w * 96 + nt * 16 + col) * 64 + (sc << 3)];
#pragma unroll
            for (int mt = 0; mt < 4; ++mt)
#pragma unroll
                for (int nt = 0; nt < 6; ++nt)
                    acc[mt][nt] = __builtin_amdgcn_mfma_f32_16x16x32_f16(
                        a[mt], bf[nt], acc[mt][nt], 0, 0, 0);
        }
        __syncthreads();
    }

    // ---- epilogue: bias add into LDS (reuse Bs as Cs[64][384]), coalesced out ----
    const float* bp[3] = {bq, bk, bv};
    _Float16* Cs = Bs;
#pragma unroll
    for (int nt = 0; nt < 6; ++nt) {
        const int n16 = w * 96 + nt * 16;
        const int y = n16 >> 7, nl = n16 & 127;
        const float bb = bp[y][nl + col];
#pragma unroll
        for (int mt = 0; mt < 4; ++mt)
#pragma unroll
            for (int reg = 0; reg < 4; ++reg) {
                const int m = mt * 16 + quad * 4 + reg;
                Cs[m * 384 + n16 + col] = (_Float16)(acc[mt][nt][reg] + bb);
            }
    }
    __syncthreads();

    {   // Q/K rows: coalesced h8 stores
        const int m = t >> 2, seg = t & 3;
#pragma unroll
        for (int j = 0; j < 8; ++j) {
            const int n = seg * 64 + j * 8;
            const h8 v = *(const h8*)&Cs[m * 384 + n];
            if (n < 128) *(h8*)&Qh[(size_t)(m0 + m) * D_ + n] = v;
            else         *(h8*)&Kh[(size_t)(m0 + m) * D_ + (n - 128)] = v;
        }
    }
    {   // V transposed: [b][d][t]
        const int vn = t & 127, part = t >> 7;
        const int bidx = m0 >> 11, tt0 = m0 & 2047;
#pragma unroll
        for (int j = 0; j < 4; ++j) {
            const int ms = part * 32 + j * 8;
            h8 hv;
#pragma unroll
            for (int e = 0; e < 8; ++e) hv[e] = Cs[(ms + e) * 384 + 256 + vn];
            *(h8*)&Vt[((size_t)bidx * D_ + vn) * T_ + tt0 + ms] = hv;
        }
    }
}

// =============== Kernel 2: flash attention, LDS-staged, k-parity split ===============
// grid = 512: b = id&7 (XCD locality), zig-zag j for constant per-CU work.
// Block: 32 q-rows, 4 waves: qw=w&1 picks 16-row half, kp=w>>1 picks k-tile parity.
// K/V double-buffered in LDS via global_load_lds (pre-swizzled source), counted vmcnt.
__global__ __launch_bounds__(256, 2) void flash_attn(
    const _Float16* __restrict__ Qh,
    const _Float16* __restrict__ Kh,
    const _Float16* __restrict__ Vt,
    float* __restrict__ out)
{
    __shared__ __align__(16) char smem[74752];
    _Float16* Ks = (_Float16*)smem;                    // [2][64 key][128 d]  32 KB
    _Float16* Vs = (_Float16*)(smem + 32768);          // [2][128 d][64 t]    32 KB
    _Float16* PlB = (_Float16*)(smem + 65536);         // [4][16][72]          9 KB

    const int t = threadIdx.x, lane = t & 63, w = t >> 6;
    const int quad = lane >> 4, col = lane & 15;
    const int id = blockIdx.x;
    const int b = id & 7;
    const int k6 = id >> 3;
    const int j32 = (k6 < 32) ? (63 - k6) : (k6 - 32);   // pair j with 63-j per CU
    const int qbase = j32 * 32;
    const int qw = w & 1, kp = w >> 1;
    const int qrow0 = qbase + qw * 16;
    const int nk = (j32 >> 1) + 1;                       // 64-key tiles needed

    // Q fragments (A-operand), 16 rows per wave
    h8 qf[4];
    const _Float16* Qp = Qh + ((size_t)b * T_ + qrow0 + col) * D_ + quad * 8;
#pragma unroll
    for (int ks = 0; ks < 4; ++ks) qf[ks] = *(const h8*)(Qp + ks * 32);
    asm volatile("s_waitcnt vmcnt(0)" ::: "memory");     // clean vmcnt before pipeline

    f4 o[8];
#pragma unroll
    for (int i = 0; i < 8; ++i) o[i] = (f4){0.f, 0.f, 0.f, 0.f};
    float m_st[4], l_st[4];
#pragma unroll
    for (int r = 0; r < 4; ++r) { m_st[r] = -1e30f; l_st[r] = 0.f; }

    const _Float16* Kb = Kh + (size_t)b * T_ * D_;
    const _Float16* Vb = Vt + (size_t)b * D_ * T_;
    const int krl = lane >> 4, kc = lane & 15;   // K: 4 rows/issue, 16 chunks/row
    const int vrl = lane >> 3, vc = lane & 7;    // V: 8 rows/issue,  8 chunks/row

    // 8 gl_lds16 per thread per stage (4 K + 4 V) -> vmcnt counts in units of 8
    auto stage = [&](int buf, int kbase) __attribute__((always_inline)) {
        _Float16* KsB = Ks + buf * 8192;
        _Float16* VsB = Vs + buf * 8192;
#pragma unroll
        for (int i = 0; i < 4; ++i) {
            const int R = w * 16 + i * 4;                 // wave-uniform
            const int r = R + krl;
            gl_lds16(Kb + (size_t)(kbase + r) * D_ + 8 * (kc ^ (r & 7)), KsB + R * D_);
        }
#pragma unroll
        for (int i = 0; i < 4; ++i) {
            const int R = w * 32 + i * 8;
            const int d = R + vrl;
            gl_lds16(Vb + (size_t)d * T_ + kbase + 8 * (vc ^ (d & 7)), VsB + R * 64);
        }
    };

    _Float16* Pw = PlB + w * 1152;   // per-wave P scratch [16][72]

    auto step = [&](int ti, int buf, bool mask) __attribute__((always_inline)) {
        const _Float16* KsB = Ks + buf * 8192;
        const _Float16* VsB = Vs + buf * 8192;
        const int cx = col & 7;

        f4 s[4];
#pragma unroll
        for (int nt = 0; nt < 4; ++nt) s[nt] = (f4){0.f, 0.f, 0.f, 0.f};
        __builtin_amdgcn_s_setprio(1);
#pragma unroll
        for (int nt = 0; nt < 4; ++nt) {
            const int r = nt * 16 + col;
#pragma unroll
            for (int ks = 0; ks < 4; ++ks) {
                const h8 kf = *(const h8*)(KsB + r * D_ + 8 * (((ks << 2) + quad) ^ cx));
                s[nt] = __builtin_amdgcn_mfma_f32_16x16x32_f16(qf[ks], kf, s[nt], 0, 0, 0);
            }
        }
        __builtin_amdgcn_s_setprio(0);

        if (mask) {
#pragma unroll
            for (int nt = 0; nt < 4; ++nt) {
                const int key = ti * 64 + nt * 16 + col;
#pragma unroll
                for (int reg = 0; reg < 4; ++reg) {
                    const int qr = qrow0 + quad * 4 + reg;
                    const float sv = s[nt][reg] * SCALE;
                    s[nt][reg] = (key <= qr) ? sv : -1e30f;
                }
            }
        } else {
#pragma unroll
            for (int nt = 0; nt < 4; ++nt)
#pragma unroll
                for (int reg = 0; reg < 4; ++reg) s[nt][reg] *= SCALE;
        }

        float mloc[4];
#pragma unroll
        for (int reg = 0; reg < 4; ++reg)
            mloc[reg] = fmaxf(fmaxf(s[0][reg], s[1][reg]), fmaxf(s[2][reg], s[3][reg]));
#pragma unroll
        for (int off = 1; off < 16; off <<= 1)
#pragma unroll
            for (int reg = 0; reg < 4; ++reg)
                mloc[reg] = fmaxf(mloc[reg], __shfl_xor(mloc[reg], off));

        float alpha[4];
#pragma unroll
        for (int reg = 0; reg < 4; ++reg) {
            const float mn = fmaxf(m_st[reg], mloc[reg]);
            alpha[reg] = __expf(m_st[reg] - mn);
            m_st[reg] = mn;
        }
        float rs[4] = {0.f, 0.f, 0.f, 0.f};
#pragma unroll
        for (int nt = 0; nt < 4; ++nt)
#pragma unroll
            for (int reg = 0; reg < 4; ++reg) {
                const float p = __expf(s[nt][reg] - m_st[reg]);
                s[nt][reg] = p;
                rs[reg] += p;
            }
#pragma unroll
        for (int off = 1; off < 16; off <<= 1)
#pragma unroll
            for (int reg = 0; reg < 4; ++reg) rs[reg] += __shfl_xor(rs[reg], off);
#pragma unroll
        for (int reg = 0; reg < 4; ++reg) l_st[reg] = l_st[reg] * alpha[reg] + rs[reg];

#pragma unroll
        for (int n2 = 0; n2 < 8; ++n2)
#pragma unroll
            for (int reg = 0; reg < 4; ++reg) o[n2][reg] *= alpha[reg];

#pragma unroll
        for (int nt = 0; nt < 4; ++nt)
#pragma unroll
            for (int reg = 0; reg < 4; ++reg)
                Pw[(quad * 4 + reg) * 72 + nt * 16 + col] = (_Float16)s[nt][reg];
        const h8 pa0 = *(const h8*)(Pw + col * 72 + quad * 8);
        const h8 pa1 = *(const h8*)(Pw + col * 72 + 32 + quad * 8);

        __builtin_amdgcn_s_setprio(1);
#pragma unroll
        for (int n2 = 0; n2 < 8; ++n2) {
            const int d = n2 * 16 + col;
            const h8 vf0 = *(const h8*)(VsB + d * 64 + 8 * (quad ^ cx));
            const h8 vf1 = *(const h8*)(VsB + d * 64 + 8 * ((4 + quad) ^ cx));
            o[n2] = __builtin_amdgcn_mfma_f32_16x16x32_f16(pa0, vf0, o[n2], 0, 0, 0);
            o[n2] = __builtin_amdgcn_mfma_f32_16x16x32_f16(pa1, vf1, o[n2], 0, 0, 0);
        }
        __builtin_amdgcn_s_setprio(0);
    };

    // ---- pipelined main loop: counted vmcnt, raw barriers (never drain mid-loop) ----
    stage(0, 0);
    for (int ti = 0; ti < nk; ++ti) {
        const int cur = ti & 1;
        if (ti + 1 < nk) {
            stage(cur ^ 1, (ti + 1) << 6);
            asm volatile("s_waitcnt vmcnt(8)" ::: "memory");   // tile ti landed; ti+1 in flight
        } else {
            asm volatile("s_waitcnt vmcnt(0)" ::: "memory");
        }
        __builtin_amdgcn_s_barrier();
        asm volatile("" ::: "memory");
        if ((ti & 1) == kp) step(ti, cur, ti == nk - 1);
        asm volatile("" ::: "memory");
        __builtin_amdgcn_s_barrier();
        asm volatile("" ::: "memory");
    }

    // ---- merge the two parity states (flash-decoding combine), write out ----
    float* Os = (float*)smem;              // [32][128] f32 (reuses Ks area)
    float* Mx = (float*)(smem + 16384);    // [32]
    float* Lx = Mx + 32;

    __syncthreads();
    if (kp == 1) {
#pragma unroll
        for (int reg = 0; reg < 4; ++reg) {
            const int row = qw * 16 + quad * 4 + reg;
            if (col == 0) { Mx[row] = m_st[reg]; Lx[row] = l_st[reg]; }
#pragma unroll
            for (int n2 = 0; n2 < 8; ++n2)
                Os[row * D_ + n2 * 16 + col] = o[n2][reg];
        }
    }
    __syncthreads();
    if (kp == 0) {
#pragma unroll
        for (int reg = 0; reg < 4; ++reg) {
            const int row = qw * 16 + quad * 4 + reg;
            const float m1 = Mx[row], l1 = Lx[row];
            const float mN = fmaxf(m_st[reg], m1);
            const float a0 = __expf(m_st[reg] - mN);
            const float a1 = __expf(m1 - mN);
            const float inv = 1.0f / (l_st[reg] * a0 + l1 * a1);
#pragma unroll
            for (int n2 = 0; n2 < 8; ++n2) {
                const float v = (o[n2][reg] * a0 + Os[row * D_ + n2 * 16 + col] * a1) * inv;
                out[((size_t)b * T_ + qbase + row) * D_ + n2 * 16 + col] = v;
            }
        }
    }
}

extern "C" void kernel_launch(void* const* d_in, const int* in_sizes, int n_in,
                              void* d_out, int out_size, void* d_ws, size_t ws_size,
                              hipStream_t stream) {
    const float* x  = (const float*)d_in[0];
    const float* Wq = (const float*)d_in[1];
    const float* bq = (const float*)d_in[2];
    const float* Wk = (const float*)d_in[3];
    const float* bk = (const float*)d_in[4];
    const float* Wv = (const float*)d_in[5];
    const float* bv = (const float*)d_in[6];

    _Float16* Qh = (_Float16*)d_ws;                       // [B*T][D] f16
    _Float16* Kh = Qh + (size_t)B_ * T_ * D_;             // [B*T][D] f16
    _Float16* Vt = Kh + (size_t)B_ * T_ * D_;             // [B][D][T] f16
    // W f16 scratch lives in d_out (0.59 MB << 8.4 MB); consumed by qkv before
    // flash_attn overwrites d_out — stream-ordered, so safe.
    _Float16* Wh = (_Float16*)d_out;                      // [3*128][768] f16

    w_prep<<<dim3(36), dim3(256), 0, stream>>>(Wq, Wk, Wv, Wh);
    qkv_fused<<<dim3(B_ * T_ / 64), dim3(256), 0, stream>>>(
        x, Wh, bq, bk, bv, Qh, Kh, Vt);
    flash_attn<<<dim3(512), dim3(256), 0, stream>>>(Qh, Kh, Vt, (float*)d_out);
}

// Round 2
// 173.406 us; speedup vs baseline: 1.7030x; 1.0237x over previous
//
#include <hip/hip_runtime.h>

#define B_ 8
#define T_ 2048
#define E_ 768
#define D_ 128
#define SCALE 0.08838834764831845f   // 1/sqrt(128)

typedef _Float16 h8 __attribute__((ext_vector_type(8)));
typedef _Float16 h4 __attribute__((ext_vector_type(4)));
typedef float f4 __attribute__((ext_vector_type(4)));

typedef __attribute__((address_space(1))) unsigned int as1_u32;
typedef __attribute__((address_space(3))) unsigned int as3_u32;

// direct global->LDS, 16B per lane; LDS dest must be wave-uniform base (HW adds lane*16)
__device__ __forceinline__ void gl_lds16(const void* g, void* l) {
    __builtin_amdgcn_global_load_lds((const as1_u32*)g, (as3_u32*)l, 16, 0, 0);
}

// =============== Kernel 0: W (fp32 [768][128] x3) -> Wh f16 [3*128][768] ===============
__global__ __launch_bounds__(256) void w_prep(
    const float* __restrict__ Wq, const float* __restrict__ Wk,
    const float* __restrict__ Wv, _Float16* __restrict__ Wh)
{
    __shared__ float tile[64][129];
    const int y = blockIdx.x / 12, kc = blockIdx.x % 12;
    const float* W = (y == 0) ? Wq : (y == 1) ? Wk : Wv;
    const int k0 = kc * 64, t = threadIdx.x;
#pragma unroll
    for (int i = 0; i < 32; ++i) {
        const int idx = i * 256 + t;
        tile[idx >> 7][idx & 127] = W[(size_t)(k0 + (idx >> 7)) * D_ + (idx & 127)];
    }
    __syncthreads();
    const int n = t >> 1, hf = t & 1;
#pragma unroll
    for (int j = 0; j < 4; ++j) {
        const int kk = hf * 32 + j * 8;
        h8 hv;
#pragma unroll
        for (int e = 0; e < 8; ++e) hv[e] = (_Float16)tile[kk + e][n];
        *(h8*)&Wh[(size_t)(y * 128 + n) * E_ + k0 + kk] = hv;
    }
}

// =============== Kernel 1: fused QKV projection, double-buffered ===============
// grid = 256 (64-row m-tile), block = 256 (4 waves, 96 cols each). LDS 112 KB.
// Pipeline: issue x-loads(reg) + W gl_lds for k+1, MFMA on k, vmcnt(12), write As(k+1).
__global__ __launch_bounds__(256) void qkv_fused(
    const float* __restrict__ x, const _Float16* __restrict__ Wh,
    const float* __restrict__ bq, const float* __restrict__ bk,
    const float* __restrict__ bv,
    _Float16* __restrict__ Qh, _Float16* __restrict__ Kh,
    _Float16* __restrict__ Vt)
{
    __shared__ _Float16 As[2][64 * 64];     // 2 x 8 KB
    __shared__ _Float16 Bs[2][384 * 64];    // 2 x 48 KB

    const int t = threadIdx.x;
    const int lane = t & 63, w = t >> 6;
    const int quad = lane >> 4, col = lane & 15;
    const int m0 = blockIdx.x * 64;

    f4 acc[4][6];
#pragma unroll
    for (int mt = 0; mt < 4; ++mt)
#pragma unroll
        for (int nt = 0; nt < 6; ++nt) acc[mt][nt] = (f4){0.f, 0.f, 0.f, 0.f};

    const int brl = lane >> 3, bc = lane & 7;       // W-stage: 8 rows x 8 chunks
    const int xr_ = t >> 2, xcb = (t & 3) * 16;     // x-stage: row, col-base

    float4 xv[4];

#define LOAD_X(kb)                                                          \
    {   const float* xr = &x[(size_t)(m0 + xr_) * E_ + (kb) + xcb];         \
        _Pragma("unroll")                                                   \
        for (int i = 0; i < 4; ++i) xv[i] = *(const float4*)(xr + 4 * i);   }

#define STAGE_B(dst, kb)                                                    \
    _Pragma("unroll")                                                       \
    for (int i = 0; i < 12; ++i) {                                          \
        const int R = w * 96 + i * 8;                                       \
        const int r = R + brl;                                              \
        gl_lds16(Wh + (size_t)r * E_ + (kb) + 8 * (bc ^ (r & 7)), &(dst)[R * 64]); }

#define WRITE_A(dst)                                                        \
    _Pragma("unroll")                                                       \
    for (int i = 0; i < 4; ++i) {                                           \
        h4 hv; hv[0] = (_Float16)xv[i].x; hv[1] = (_Float16)xv[i].y;        \
        hv[2] = (_Float16)xv[i].z; hv[3] = (_Float16)xv[i].w;               \
        const int kk4 = xcb + 4 * i;                                        \
        *(h4*)&(dst)[xr_ * 64 + (((kk4 >> 3) ^ (xr_ & 7)) << 3) + (kk4 & 7)] = hv; }

    // ---- prologue: fill buffer 0 ----
    LOAD_X(0);
    STAGE_B(Bs[0], 0);
    asm volatile("s_waitcnt vmcnt(12)" ::: "memory");   // x landed; 12 W-loads flying
    WRITE_A(As[0]);
    __syncthreads();                                    // drains W loads too

#pragma unroll 2
    for (int it = 0; it < 12; ++it) {
        const int c = it & 1;
        if (it < 11) {
            LOAD_X((it + 1) * 64);
            STAGE_B(Bs[c ^ 1], (it + 1) * 64);
        }
        // ---- MFMA on buffer c ----
#pragma unroll
        for (int ks = 0; ks < 2; ++ks) {
            const int sc = ((ks << 2) + quad) ^ (col & 7);
            h8 a[4], bf[6];
#pragma unroll
            for (int mt = 0; mt < 4; ++mt)
                a[mt] = *(const h8*)&As[c][(mt * 16 + col) * 64 + (sc << 3)];
#pragma unroll
            for (int nt = 0; nt < 6; ++nt)
                bf[nt] = *(const h8*)&Bs[c][(w * 96 + nt * 16 + col) * 64 + (sc << 3)];
#pragma unroll
            for (int mt = 0; mt < 4; ++mt)
#pragma unroll
                for (int nt = 0; nt < 6; ++nt)
                    acc[mt][nt] = __builtin_amdgcn_mfma_f32_16x16x32_f16(
                        a[mt], bf[nt], acc[mt][nt], 0, 0, 0);
        }
        if (it < 11) {
            asm volatile("s_waitcnt vmcnt(12)" ::: "memory");   // x regs ready
            WRITE_A(As[c ^ 1]);
        }
        __syncthreads();
    }

    // ---- epilogue: bias add into LDS (Cs[64][384] = Bs[0]), coalesced out ----
    const float* bp[3] = {bq, bk, bv};
    _Float16* Cs = &Bs[0][0];
#pragma unroll
    for (int nt = 0; nt < 6; ++nt) {
        const int n16 = w * 96 + nt * 16;
        const int y = n16 >> 7, nl = n16 & 127;
        const float bb = bp[y][nl + col];
#pragma unroll
        for (int mt = 0; mt < 4; ++mt)
#pragma unroll
            for (int reg = 0; reg < 4; ++reg) {
                const int m = mt * 16 + quad * 4 + reg;
                Cs[m * 384 + n16 + col] = (_Float16)(acc[mt][nt][reg] + bb);
            }
    }
    __syncthreads();

    {   // Q/K rows: coalesced h8 stores
        const int m = t >> 2, seg = t & 3;
#pragma unroll
        for (int j = 0; j < 8; ++j) {
            const int n = seg * 64 + j * 8;
            const h8 v = *(const h8*)&Cs[m * 384 + n];
            if (n < 128) *(h8*)&Qh[(size_t)(m0 + m) * D_ + n] = v;
            else         *(h8*)&Kh[(size_t)(m0 + m) * D_ + (n - 128)] = v;
        }
    }
    {   // V transposed: [b][d][t]
        const int vn = t & 127, part = t >> 7;
        const int bidx = m0 >> 11, tt0 = m0 & 2047;
#pragma unroll
        for (int j = 0; j < 4; ++j) {
            const int ms = part * 32 + j * 8;
            h8 hv;
#pragma unroll
            for (int e = 0; e < 8; ++e) hv[e] = Cs[(ms + e) * 384 + 256 + vn];
            *(h8*)&Vt[((size_t)bidx * D_ + vn) * T_ + tt0 + ms] = hv;
        }
    }
#undef LOAD_X
#undef STAGE_B
#undef WRITE_A
}

// =============== Kernel 2: flash attention — all waves compute every tile ===============
// grid = 512, heavy-first (j32 = 63 - id>>3), b = id&7 (XCD-batch locality).
// 4 waves = qw(2 row-halves) x kh(2 key-halves of each 64-key tile).
// kh softmax states merged at the end (flash-decoding combine).
__global__ __launch_bounds__(256, 2) void flash_attn(
    const _Float16* __restrict__ Qh,
    const _Float16* __restrict__ Kh,
    const _Float16* __restrict__ Vt,
    float* __restrict__ out)
{
    __shared__ __align__(16) char smem[70656];
    _Float16* Ks = (_Float16*)smem;                    // [2][64 key][128 d]  32 KB
    _Float16* Vs = (_Float16*)(smem + 32768);          // [2][128 d][64 t]    32 KB
    _Float16* Pb = (_Float16*)(smem + 65536);          // [4][16][40]          5 KB

    const int t = threadIdx.x, lane = t & 63, w = t >> 6;
    const int quad = lane >> 4, col = lane & 15;
    const int id = blockIdx.x;
    const int b = id & 7;
    const int j32 = 63 - (id >> 3);                    // heaviest blocks first
    const int qw = w & 1, kh = w >> 1;
    const int qbase = j32 * 32;
    const int qrow0 = qbase + qw * 16;
    const int nk = (j32 >> 1) + 1;

    // Q fragments: A row = col, k = quad*8 within each 32-k block
    h8 qf[4];
    const _Float16* Qp = Qh + ((size_t)b * T_ + qrow0 + col) * D_ + quad * 8;
#pragma unroll
    for (int ks = 0; ks < 4; ++ks) qf[ks] = *(const h8*)(Qp + ks * 32);
    asm volatile("s_waitcnt vmcnt(0)" ::: "memory");   // keep vmcnt clean for counting

    f4 o[8];
#pragma unroll
    for (int i = 0; i < 8; ++i) o[i] = (f4){0.f, 0.f, 0.f, 0.f};
    float m_st[4], l_st[4];
#pragma unroll
    for (int r = 0; r < 4; ++r) { m_st[r] = -1e30f; l_st[r] = 0.f; }

    const _Float16* Kb = Kh + (size_t)b * T_ * D_;
    const _Float16* Vb = Vt + (size_t)b * D_ * T_;
    const int krl = lane >> 4, kc = lane & 15;   // K: 4 rows x 16 chunks
    const int vrl = lane >> 3, vc = lane & 7;    // V: 8 rows x 8 chunks
    const int cx = col & 7;

    // 8 gl_lds per thread per stage (4 K + 4 V)
    auto stage = [&](int buf, int kbase) __attribute__((always_inline)) {
        _Float16* KsB = Ks + buf * 8192;
        _Float16* VsB = Vs + buf * 8192;
#pragma unroll
        for (int i = 0; i < 4; ++i) {
            const int R = w * 16 + i * 4;
            const int r = R + krl;
            gl_lds16(Kb + (size_t)(kbase + r) * D_ + 8 * (kc ^ (r & 7)), KsB + R * D_);
        }
#pragma unroll
        for (int i = 0; i < 4; ++i) {
            const int R = w * 32 + i * 8;
            const int d = R + vrl;
            gl_lds16(Vb + (size_t)d * T_ + kbase + 8 * (vc ^ (d & 7)), VsB + R * 64);
        }
    };

    _Float16* Pw = Pb + w * 640;   // [16][40] h16 per wave

    auto step = [&](int ti, int buf, bool mask) __attribute__((always_inline)) {
        const _Float16* KsB = Ks + buf * 8192;
        const _Float16* VsB = Vs + buf * 8192;

        // ---- QK^T: this wave's 32-key half (2 nt x 4 ks MFMA) ----
        f4 s[2];
        s[0] = (f4){0.f, 0.f, 0.f, 0.f};
        s[1] = (f4){0.f, 0.f, 0.f, 0.f};
        __builtin_amdgcn_s_setprio(1);
#pragma unroll
        for (int nt = 0; nt < 2; ++nt) {
            const int r = kh * 32 + nt * 16 + col;
#pragma unroll
            for (int ks = 0; ks < 4; ++ks) {
                const h8 kf = *(const h8*)(KsB + r * D_ + 8 * (((ks << 2) + quad) ^ cx));
                s[nt] = __builtin_amdgcn_mfma_f32_16x16x32_f16(qf[ks], kf, s[nt], 0, 0, 0);
            }
        }
        __builtin_amdgcn_s_setprio(0);

        if (mask) {
#pragma unroll
            for (int nt = 0; nt < 2; ++nt) {
                const int key = ti * 64 + kh * 32 + nt * 16 + col;
#pragma unroll
                for (int reg = 0; reg < 4; ++reg) {
                    const int qr = qrow0 + quad * 4 + reg;
                    const float sv = s[nt][reg] * SCALE;
                    s[nt][reg] = (key <= qr) ? sv : -1e30f;
                }
            }
        } else {
#pragma unroll
            for (int nt = 0; nt < 2; ++nt)
#pragma unroll
                for (int reg = 0; reg < 4; ++reg) s[nt][reg] *= SCALE;
        }

        // ---- row max over 32 keys: in-reg + 4 shfl rounds over 16 cols ----
        float mloc[4];
#pragma unroll
        for (int reg = 0; reg < 4; ++reg) mloc[reg] = fmaxf(s[0][reg], s[1][reg]);
#pragma unroll
        for (int off = 1; off < 16; off <<= 1)
#pragma unroll
            for (int reg = 0; reg < 4; ++reg)
                mloc[reg] = fmaxf(mloc[reg], __shfl_xor(mloc[reg], off));

        // ---- defer-max: rescale only when the running max grows ----
        bool grow = (mloc[0] > m_st[0]) | (mloc[1] > m_st[1]) |
                    (mloc[2] > m_st[2]) | (mloc[3] > m_st[3]);
        if (__any((int)grow)) {
#pragma unroll
            for (int reg = 0; reg < 4; ++reg) {
                const float mn = fmaxf(m_st[reg], mloc[reg]);
                const float alpha = __expf(m_st[reg] - mn);
                m_st[reg] = mn;
                l_st[reg] *= alpha;
#pragma unroll
                for (int n2 = 0; n2 < 8; ++n2) o[n2][reg] *= alpha;
            }
        }

        float rs[4] = {0.f, 0.f, 0.f, 0.f};
#pragma unroll
        for (int nt = 0; nt < 2; ++nt)
#pragma unroll
            for (int reg = 0; reg < 4; ++reg) {
                const float p = __expf(s[nt][reg] - m_st[reg]);
                s[nt][reg] = p;
                rs[reg] += p;
            }
#pragma unroll
        for (int off = 1; off < 16; off <<= 1)
#pragma unroll
            for (int reg = 0; reg < 4; ++reg) rs[reg] += __shfl_xor(rs[reg], off);
#pragma unroll
        for (int reg = 0; reg < 4; ++reg) l_st[reg] += rs[reg];

        // ---- P to LDS (A-frag relayout), then PV: 8 MFMA over 32 keys ----
#pragma unroll
        for (int nt = 0; nt < 2; ++nt)
#pragma unroll
            for (int reg = 0; reg < 4; ++reg)
                Pw[(quad * 4 + reg) * 40 + nt * 16 + col] = (_Float16)s[nt][reg];
        const h8 pa = *(const h8*)(Pw + col * 40 + quad * 8);

        __builtin_amdgcn_s_setprio(1);
#pragma unroll
        for (int n2 = 0; n2 < 8; ++n2) {
            const int d = n2 * 16 + col;
            const h8 vf = *(const h8*)(VsB + d * 64 + 8 * ((kh * 4 + quad) ^ (d & 7)));
            o[n2] = __builtin_amdgcn_mfma_f32_16x16x32_f16(pa, vf, o[n2], 0, 0, 0);
        }
        __builtin_amdgcn_s_setprio(0);
    };

    // ---- main loop: counted vmcnt, raw barriers ----
    stage(0, 0);
    const bool evenJ = ((j32 & 1) == 0);
    for (int ti = 0; ti < nk; ++ti) {
        const int cur = ti & 1;
        if (ti + 1 < nk) {
            stage(cur ^ 1, (ti + 1) << 6);
            asm volatile("s_waitcnt vmcnt(8)" ::: "memory");   // tile ti landed
        } else {
            asm volatile("s_waitcnt vmcnt(0)" ::: "memory");
        }
        __builtin_amdgcn_s_barrier();
        const bool last = (ti == nk - 1);
        // even j32: last tile's kh=1 half is entirely beyond the diagonal -> skip
        if (!(last && evenJ && kh == 1)) {
            const bool mask = last && (kh == (j32 & 1));
            step(ti, cur, mask);
        }
        __builtin_amdgcn_s_barrier();
    }

    // ---- merge kh=0 and kh=1 states (flash-decoding combine) ----
    float* Os = (float*)smem;              // [32][128] f32 (reuses Ks area)
    float* Mx = (float*)(smem + 16384);    // [32]
    float* Lx = Mx + 32;

    __syncthreads();
    if (kh == 1) {
#pragma unroll
        for (int reg = 0; reg < 4; ++reg) {
            const int row = qw * 16 + quad * 4 + reg;
            if (col == 0) { Mx[row] = m_st[reg]; Lx[row] = l_st[reg]; }
#pragma unroll
            for (int n2 = 0; n2 < 8; ++n2)
                Os[row * D_ + n2 * 16 + col] = o[n2][reg];
        }
    }
    __syncthreads();
    if (kh == 0) {
#pragma unroll
        for (int reg = 0; reg < 4; ++reg) {
            const int row = qw * 16 + quad * 4 + reg;
            const float m1 = Mx[row], l1 = Lx[row];
            const float mN = fmaxf(m_st[reg], m1);
            const float a0 = __expf(m_st[reg] - mN);
            const float a1 = __expf(m1 - mN);
            const float inv = 1.0f / (l_st[reg] * a0 + l1 * a1);
#pragma unroll
            for (int n2 = 0; n2 < 8; ++n2) {
                const float v = (o[n2][reg] * a0 + Os[row * D_ + n2 * 16 + col] * a1) * inv;
                out[((size_t)b * T_ + qbase + row) * D_ + n2 * 16 + col] = v;
            }
        }
    }
}

extern "C" void kernel_launch(void* const* d_in, const int* in_sizes, int n_in,
                              void* d_out, int out_size, void* d_ws, size_t ws_size,
                              hipStream_t stream) {
    const float* x  = (const float*)d_in[0];
    const float* Wq = (const float*)d_in[1];
    const float* bq = (const float*)d_in[2];
    const float* Wk = (const float*)d_in[3];
    const float* bk = (const float*)d_in[4];
    const float* Wv = (const float*)d_in[5];
    const float* bv = (const float*)d_in[6];

    _Float16* Qh = (_Float16*)d_ws;                       // [B*T][D] f16
    _Float16* Kh = Qh + (size_t)B_ * T_ * D_;             // [B*T][D] f16
    _Float16* Vt = Kh + (size_t)B_ * T_ * D_;             // [B][D][T] f16
    // W f16 scratch in d_out (0.59 MB << 8.4 MB); consumed before flash_attn writes.
    _Float16* Wh = (_Float16*)d_out;                      // [3*128][768] f16

    w_prep<<<dim3(36), dim3(256), 0, stream>>>(Wq, Wk, Wv, Wh);
    qkv_fused<<<dim3(B_ * T_ / 64), dim3(256), 0, stream>>>(
        x, Wh, bq, bk, bv, Qh, Kh, Vt);
    flash_attn<<<dim3(512), dim3(256), 0, stream>>>(Qh, Kh, Vt, (float*)d_out);
}

// Round 3
// 163.094 us; speedup vs baseline: 1.8107x; 1.0632x over previous
//
#include <hip/hip_runtime.h>

#define B_ 8
#define T_ 2048
#define E_ 768
#define D_ 128
// scores kept in exp2 domain: scale = (1/sqrt(128)) * log2(e)
#define SCALE2 (0.08838834764831845f * 1.4426950408889634f)

typedef _Float16 h8 __attribute__((ext_vector_type(8)));
typedef _Float16 h4 __attribute__((ext_vector_type(4)));
typedef _Float16 h2 __attribute__((ext_vector_type(2)));
typedef float f4 __attribute__((ext_vector_type(4)));

typedef __attribute__((address_space(1))) unsigned int as1_u32;
typedef __attribute__((address_space(3))) unsigned int as3_u32;

__device__ __forceinline__ void gl_lds16(const void* g, void* l) {
    __builtin_amdgcn_global_load_lds((const as1_u32*)g, (as3_u32*)l, 16, 0, 0);
}

// =============== Kernel 0: W (fp32 [768][128] x3) -> Wh f16 [3*128][768] ===============
__global__ __launch_bounds__(256) void w_prep(
    const float* __restrict__ Wq, const float* __restrict__ Wk,
    const float* __restrict__ Wv, _Float16* __restrict__ Wh)
{
    __shared__ float tile[64][129];
    const int y = blockIdx.x / 12, kc = blockIdx.x % 12;
    const float* W = (y == 0) ? Wq : (y == 1) ? Wk : Wv;
    const int k0 = kc * 64, t = threadIdx.x;
#pragma unroll
    for (int i = 0; i < 32; ++i) {
        const int idx = i * 256 + t;
        tile[idx >> 7][idx & 127] = W[(size_t)(k0 + (idx >> 7)) * D_ + (idx & 127)];
    }
    __syncthreads();
    const int n = t >> 1, hf = t & 1;
#pragma unroll
    for (int j = 0; j < 4; ++j) {
        const int kk = hf * 32 + j * 8;
        h8 hv;
#pragma unroll
        for (int e = 0; e < 8; ++e) hv[e] = (_Float16)tile[kk + e][n];
        *(h8*)&Wh[(size_t)(y * 128 + n) * E_ + k0 + kk] = hv;
    }
}

// =============== Kernel 1: fused QKV projection ===============
// LDS 64 KB (As x2 + Bs x1) -> 2 blocks/CU. x prefetched 2 tiles ahead in regs;
// W staged via gl_lds with counted vmcnt(4) (x prefetch stays in flight).
__global__ __launch_bounds__(256, 2) void qkv_fused(
    const float* __restrict__ x, const _Float16* __restrict__ Wh,
    const float* __restrict__ bq, const float* __restrict__ bk,
    const float* __restrict__ bv,
    _Float16* __restrict__ Qh, _Float16* __restrict__ Kh,
    _Float16* __restrict__ Vt)
{
    __shared__ _Float16 As[2][64 * 64];     // 16 KB
    __shared__ _Float16 Bs[384 * 64];       // 48 KB

    const int t = threadIdx.x;
    const int lane = t & 63, w = t >> 6;
    const int quad = lane >> 4, col = lane & 15;
    const int m0 = blockIdx.x * 64;

    f4 acc[4][6];
#pragma unroll
    for (int mt = 0; mt < 4; ++mt)
#pragma unroll
        for (int nt = 0; nt < 6; ++nt) acc[mt][nt] = (f4){0.f, 0.f, 0.f, 0.f};

    const int brl = lane >> 3, bc = lane & 7;       // W-stage: 8 rows x 8 chunks
    const int xr_ = t >> 2, xcb = (t & 3) * 16;     // x-stage: row, col-base

    float4 xv[4];

#define LOAD_X(kb)                                                          \
    {   const float* xr = &x[(size_t)(m0 + xr_) * E_ + (kb) + xcb];         \
        _Pragma("unroll")                                                   \
        for (int i = 0; i < 4; ++i) xv[i] = *(const float4*)(xr + 4 * i);   }

#define STAGE_B(kb)                                                         \
    _Pragma("unroll")                                                       \
    for (int i = 0; i < 12; ++i) {                                          \
        const int R = w * 96 + i * 8;                                       \
        const int r = R + brl;                                              \
        gl_lds16(Wh + (size_t)r * E_ + (kb) + 8 * (bc ^ (r & 7)), &Bs[R * 64]); }

#define WRITE_A(dst)                                                        \
    _Pragma("unroll")                                                       \
    for (int i = 0; i < 4; ++i) {                                           \
        h4 hv; hv[0] = (_Float16)xv[i].x; hv[1] = (_Float16)xv[i].y;        \
        hv[2] = (_Float16)xv[i].z; hv[3] = (_Float16)xv[i].w;               \
        const int kk4 = xcb + 4 * i;                                        \
        *(h4*)&(dst)[xr_ * 64 + (((kk4 >> 3) ^ (xr_ & 7)) << 3) + (kk4 & 7)] = hv; }

    // ---- prologue ----
    LOAD_X(0);
    STAGE_B(0);
    asm volatile("s_waitcnt vmcnt(12)" ::: "memory");   // x(0) landed
    WRITE_A(As[0]);
    LOAD_X(64);                                         // prefetch x(1)
    asm volatile("s_waitcnt vmcnt(4) lgkmcnt(0)" ::: "memory"); // B(0) landed
    __builtin_amdgcn_s_barrier();

#pragma unroll 2
    for (int it = 0; it < 12; ++it) {
        const int c = it & 1;
        // ---- MFMA on As[c], Bs ----
#pragma unroll
        for (int ks = 0; ks < 2; ++ks) {
            const int sc = ((ks << 2) + quad) ^ (col & 7);
            h8 a[4], bf[6];
#pragma unroll
            for (int mt = 0; mt < 4; ++mt)
                a[mt] = *(const h8*)&As[c][(mt * 16 + col) * 64 + (sc << 3)];
#pragma unroll
            for (int nt = 0; nt < 6; ++nt)
                bf[nt] = *(const h8*)&Bs[(w * 96 + nt * 16 + col) * 64 + (sc << 3)];
#pragma unroll
            for (int mt = 0; mt < 4; ++mt)
#pragma unroll
                for (int nt = 0; nt < 6; ++nt)
                    acc[mt][nt] = __builtin_amdgcn_mfma_f32_16x16x32_f16(
                        a[mt], bf[nt], acc[mt][nt], 0, 0, 0);
        }
        if (it < 11) {
            asm volatile("s_waitcnt vmcnt(0)" ::: "memory");    // x(it+1) in regs
            WRITE_A(As[c ^ 1]);
            asm volatile("s_waitcnt lgkmcnt(0)" ::: "memory");
            __builtin_amdgcn_s_barrier();                       // Bs reads done everywhere
            STAGE_B((it + 1) * 64);
            if (it < 10) {
                LOAD_X((it + 2) * 64);
                asm volatile("s_waitcnt vmcnt(4)" ::: "memory"); // B(it+1) landed
            } else {
                asm volatile("s_waitcnt vmcnt(0)" ::: "memory");
            }
            __builtin_amdgcn_s_barrier();
        } else {
            asm volatile("s_waitcnt vmcnt(0)" ::: "memory");
            __builtin_amdgcn_s_barrier();                       // before Cs reuse
        }
    }

    // ---- epilogue: bias add into LDS (Cs[64][384] = Bs), coalesced out ----
    const float* bp[3] = {bq, bk, bv};
    _Float16* Cs = &Bs[0];
#pragma unroll
    for (int nt = 0; nt < 6; ++nt) {
        const int n16 = w * 96 + nt * 16;
        const int y = n16 >> 7, nl = n16 & 127;
        const float bb = bp[y][nl + col];
#pragma unroll
        for (int mt = 0; mt < 4; ++mt)
#pragma unroll
            for (int reg = 0; reg < 4; ++reg) {
                const int m = mt * 16 + quad * 4 + reg;
                Cs[m * 384 + n16 + col] = (_Float16)(acc[mt][nt][reg] + bb);
            }
    }
    __syncthreads();

    {   // Q/K rows: coalesced h8 stores
        const int m = t >> 2, seg = t & 3;
#pragma unroll
        for (int j = 0; j < 8; ++j) {
            const int n = seg * 64 + j * 8;
            const h8 v = *(const h8*)&Cs[m * 384 + n];
            if (n < 128) *(h8*)&Qh[(size_t)(m0 + m) * D_ + n] = v;
            else         *(h8*)&Kh[(size_t)(m0 + m) * D_ + (n - 128)] = v;
        }
    }
    {   // V transposed: [b][d][t]
        const int vn = t & 127, part = t >> 7;
        const int bidx = m0 >> 11, tt0 = m0 & 2047;
#pragma unroll
        for (int j = 0; j < 4; ++j) {
            const int ms = part * 32 + j * 8;
            h8 hv;
#pragma unroll
            for (int e = 0; e < 8; ++e) hv[e] = Cs[(ms + e) * 384 + 256 + vn];
            *(h8*)&Vt[((size_t)bidx * D_ + vn) * T_ + tt0 + ms] = hv;
        }
    }
#undef LOAD_X
#undef STAGE_B
#undef WRITE_A
}

// =============== Kernel 2: flash attention, swapped-QK^T in-register softmax ===============
// S^T layout: lane holds 8 keys for ONE q-row (q = col) -> softmax reduce is
// 7 in-reg ops + 2 shfl rounds (quad combine). P relayout: 4 packed h2 LDS
// writes + 1 ds_read_b128. PV computes O^T = V^T . P^T (same V loads).
__global__ __launch_bounds__(256, 2) void flash_attn(
    const _Float16* __restrict__ Qh,
    const _Float16* __restrict__ Kh,
    const _Float16* __restrict__ Vt,
    float* __restrict__ out)
{
    __shared__ __align__(16) char smem[70656];
    _Float16* Ks = (_Float16*)smem;                    // [2][64 key][128 d]  32 KB
    _Float16* Vs = (_Float16*)(smem + 32768);          // [2][128 d][64 t]    32 KB
    _Float16* Pb = (_Float16*)(smem + 65536);          // [4][16 q][40 key]    5 KB

    const int t = threadIdx.x, lane = t & 63, w = t >> 6;
    const int quad = lane >> 4, col = lane & 15;
    const int id = blockIdx.x;
    const int b = id & 7;
    const int j32 = 63 - (id >> 3);                    // heaviest blocks first
    const int qw = w & 1, kh = w >> 1;
    const int qbase = j32 * 32;
    const int qrow0 = qbase + qw * 16;
    const int nk = (j32 >> 1) + 1;

    h8 qf[4];
    const _Float16* Qp = Qh + ((size_t)b * T_ + qrow0 + col) * D_ + quad * 8;
#pragma unroll
    for (int ks = 0; ks < 4; ++ks) qf[ks] = *(const h8*)(Qp + ks * 32);
    asm volatile("s_waitcnt vmcnt(0)" ::: "memory");   // keep vmcnt clean for counting

    f4 o[8];
#pragma unroll
    for (int i = 0; i < 8; ++i) o[i] = (f4){0.f, 0.f, 0.f, 0.f};
    float m_st = -1e30f, l_st = 0.f;

    const _Float16* Kb = Kh + (size_t)b * T_ * D_;
    const _Float16* Vb = Vt + (size_t)b * D_ * T_;
    const int krl = lane >> 4, kc = lane & 15;
    const int vrl = lane >> 3, vc = lane & 7;
    const int cx = col & 7;

    auto stage = [&](int buf, int kbase) __attribute__((always_inline)) {
        _Float16* KsB = Ks + buf * 8192;
        _Float16* VsB = Vs + buf * 8192;
#pragma unroll
        for (int i = 0; i < 4; ++i) {
            const int R = w * 16 + i * 4;
            const int r = R + krl;
            gl_lds16(Kb + (size_t)(kbase + r) * D_ + 8 * (kc ^ (r & 7)), KsB + R * D_);
        }
#pragma unroll
        for (int i = 0; i < 4; ++i) {
            const int R = w * 32 + i * 8;
            const int d = R + vrl;
            gl_lds16(Vb + (size_t)d * T_ + kbase + 8 * (vc ^ (d & 7)), VsB + R * 64);
        }
    };

    _Float16* Pw = Pb + w * 640;   // [16 q][40 key-pad] per wave

    auto step = [&](int ti, int buf, bool mask) __attribute__((always_inline)) {
        const _Float16* KsB = Ks + buf * 8192;
        const _Float16* VsB = Vs + buf * 8192;

        // ---- QK^T swapped: s^T[key][q], lane: q=col, keys nt*16+quad*4+reg ----
        f4 s[2];
        s[0] = (f4){0.f, 0.f, 0.f, 0.f};
        s[1] = (f4){0.f, 0.f, 0.f, 0.f};
        __builtin_amdgcn_s_setprio(1);
#pragma unroll
        for (int nt = 0; nt < 2; ++nt) {
            const int r = kh * 32 + nt * 16 + col;
#pragma unroll
            for (int ks = 0; ks < 4; ++ks) {
                const h8 kf = *(const h8*)(KsB + r * D_ + 8 * (((ks << 2) + quad) ^ cx));
                s[nt] = __builtin_amdgcn_mfma_f32_16x16x32_f16(kf, qf[ks], s[nt], 0, 0, 0);
            }
        }
        __builtin_amdgcn_s_setprio(0);

        const int qr = qrow0 + col;
        if (mask) {
#pragma unroll
            for (int nt = 0; nt < 2; ++nt) {
                const int key = ti * 64 + kh * 32 + nt * 16 + quad * 4;
#pragma unroll
                for (int reg = 0; reg < 4; ++reg) {
                    const float sv = s[nt][reg] * SCALE2;
                    s[nt][reg] = (key + reg <= qr) ? sv : -1e30f;
                }
            }
        } else {
#pragma unroll
            for (int nt = 0; nt < 2; ++nt)
#pragma unroll
                for (int reg = 0; reg < 4; ++reg) s[nt][reg] *= SCALE2;
        }

        // ---- row max: 7 in-reg + 2 shfl rounds (quad combine) ----
        float mloc = fmaxf(fmaxf(fmaxf(s[0][0], s[0][1]), fmaxf(s[0][2], s[0][3])),
                           fmaxf(fmaxf(s[1][0], s[1][1]), fmaxf(s[1][2], s[1][3])));
        mloc = fmaxf(mloc, __shfl_xor(mloc, 16));
        mloc = fmaxf(mloc, __shfl_xor(mloc, 32));

        // ---- defer-max rescale ----
        if (__any((int)(mloc > m_st))) {
            const float mn = fmaxf(m_st, mloc);
            const float al = __builtin_amdgcn_exp2f(m_st - mn);
            m_st = mn;
            l_st *= al;
#pragma unroll
            for (int n2 = 0; n2 < 8; ++n2) o[n2] *= al;
        }

        float rs = 0.f;
#pragma unroll
        for (int nt = 0; nt < 2; ++nt)
#pragma unroll
            for (int reg = 0; reg < 4; ++reg) {
                const float p = __builtin_amdgcn_exp2f(s[nt][reg] - m_st);
                s[nt][reg] = p;
                rs += p;
            }
        rs += __shfl_xor(rs, 16);
        rs += __shfl_xor(rs, 32);
        l_st += rs;

        // ---- P^T -> B-frag relayout: 4 packed h2 writes + 1 b128 read ----
#pragma unroll
        for (int nt = 0; nt < 2; ++nt) {
            h2 p0; p0[0] = (_Float16)s[nt][0]; p0[1] = (_Float16)s[nt][1];
            h2 p1; p1[0] = (_Float16)s[nt][2]; p1[1] = (_Float16)s[nt][3];
            *(h2*)&Pw[col * 40 + nt * 16 + quad * 4]     = p0;
            *(h2*)&Pw[col * 40 + nt * 16 + quad * 4 + 2] = p1;
        }
        const h8 pa = *(const h8*)&Pw[col * 40 + quad * 8];

        // ---- PV: O^T[d][q] += V^T[d][k] P^T[k][q] ----
        __builtin_amdgcn_s_setprio(1);
#pragma unroll
        for (int n2 = 0; n2 < 8; ++n2) {
            const int d = n2 * 16 + col;
            const h8 vf = *(const h8*)(VsB + d * 64 + 8 * ((kh * 4 + quad) ^ (d & 7)));
            o[n2] = __builtin_amdgcn_mfma_f32_16x16x32_f16(vf, pa, o[n2], 0, 0, 0);
        }
        __builtin_amdgcn_s_setprio(0);
    };

    // ---- main loop: counted vmcnt, raw barriers ----
    stage(0, 0);
    const bool evenJ = ((j32 & 1) == 0);
    for (int ti = 0; ti < nk; ++ti) {
        const int cur = ti & 1;
        if (ti + 1 < nk) {
            stage(cur ^ 1, (ti + 1) << 6);
            asm volatile("s_waitcnt vmcnt(8)" ::: "memory");   // tile ti landed
        } else {
            asm volatile("s_waitcnt vmcnt(0)" ::: "memory");
        }
        __builtin_amdgcn_s_barrier();
        const bool last = (ti == nk - 1);
        if (!(last && evenJ && kh == 1)) {
            const bool mask = last && (kh == (j32 & 1));
            step(ti, cur, mask);
        }
        __builtin_amdgcn_s_barrier();
    }

    // ---- merge kh halves in O^T space, then coalesced store ----
    float* Os = (float*)smem;              // [32 q][132 d] f32 (16.9 KB, Ks area)
    float* Mx = (float*)(smem + 16896);    // [32]
    float* Lx = Mx + 32;                   // [32]
    const int qloc = qw * 16 + col;

    __syncthreads();
    if (kh == 1) {
        if (quad == 0) { Mx[qloc] = m_st; Lx[qloc] = l_st; }
#pragma unroll
        for (int n2 = 0; n2 < 8; ++n2)
#pragma unroll
            for (int reg = 0; reg < 4; ++reg)
                Os[qloc * 132 + n2 * 16 + quad * 4 + reg] = o[n2][reg];
    }
    __syncthreads();
    if (kh == 0) {
        const float m1 = Mx[qloc], l1 = Lx[qloc];
        const float mN = fmaxf(m_st, m1);
        const float a0 = __builtin_amdgcn_exp2f(m_st - mN);
        const float a1 = __builtin_amdgcn_exp2f(m1 - mN);
        const float inv = 1.0f / (l_st * a0 + l1 * a1);
#pragma unroll
        for (int n2 = 0; n2 < 8; ++n2)
#pragma unroll
            for (int reg = 0; reg < 4; ++reg) {
                const int d = n2 * 16 + quad * 4 + reg;
                Os[qloc * 132 + d] = (o[n2][reg] * a0 + Os[qloc * 132 + d] * a1) * inv;
            }
    }
    __syncthreads();
    {   // coalesced f32 store: thread -> (row, 16-float segment)
        const int row = t >> 3, d0 = (t & 7) * 16;
        float* op = &out[((size_t)b * T_ + qbase + row) * D_ + d0];
#pragma unroll
        for (int j = 0; j < 4; ++j)
            *(float4*)(op + j * 4) = *(const float4*)&Os[row * 132 + d0 + j * 4];
    }
}

extern "C" void kernel_launch(void* const* d_in, const int* in_sizes, int n_in,
                              void* d_out, int out_size, void* d_ws, size_t ws_size,
                              hipStream_t stream) {
    const float* x  = (const float*)d_in[0];
    const float* Wq = (const float*)d_in[1];
    const float* bq = (const float*)d_in[2];
    const float* Wk = (const float*)d_in[3];
    const float* bk = (const float*)d_in[4];
    const float* Wv = (const float*)d_in[5];
    const float* bv = (const float*)d_in[6];

    _Float16* Qh = (_Float16*)d_ws;                       // [B*T][D] f16
    _Float16* Kh = Qh + (size_t)B_ * T_ * D_;             // [B*T][D] f16
    _Float16* Vt = Kh + (size_t)B_ * T_ * D_;             // [B][D][T] f16
    _Float16* Wh = (_Float16*)d_out;                      // [3*128][768] f16 (scratch)

    w_prep<<<dim3(36), dim3(256), 0, stream>>>(Wq, Wk, Wv, Wh);
    qkv_fused<<<dim3(B_ * T_ / 64), dim3(256), 0, stream>>>(
        x, Wh, bq, bk, bv, Qh, Kh, Vt);
    flash_attn<<<dim3(512), dim3(256), 0, stream>>>(Qh, Kh, Vt, (float*)d_out);
}

// Round 4
// 153.001 us; speedup vs baseline: 1.9301x; 1.0660x over previous
//
#include <hip/hip_runtime.h>

#define B_ 8
#define T_ 2048
#define E_ 768
#define D_ 128
// scores kept in exp2 domain: scale = (1/sqrt(128)) * log2(e)
#define SCALE2 (0.08838834764831845f * 1.4426950408889634f)

typedef _Float16 h8 __attribute__((ext_vector_type(8)));
typedef _Float16 h4 __attribute__((ext_vector_type(4)));
typedef _Float16 h2 __attribute__((ext_vector_type(2)));
typedef float f4 __attribute__((ext_vector_type(4)));

typedef __attribute__((address_space(1))) unsigned int as1_u32;
typedef __attribute__((address_space(3))) unsigned int as3_u32;

__device__ __forceinline__ void gl_lds16(const void* g, void* l) {
    __builtin_amdgcn_global_load_lds((const as1_u32*)g, (as3_u32*)l, 16, 0, 0);
}

// =============== Kernel 0: W (fp32 [768][128] x3) -> Wh f16 [3*128][768] ===============
__global__ __launch_bounds__(256) void w_prep(
    const float* __restrict__ Wq, const float* __restrict__ Wk,
    const float* __restrict__ Wv, _Float16* __restrict__ Wh)
{
    __shared__ float tile[64][129];
    const int y = blockIdx.x / 12, kc = blockIdx.x % 12;
    const float* W = (y == 0) ? Wq : (y == 1) ? Wk : Wv;
    const int k0 = kc * 64, t = threadIdx.x;
#pragma unroll
    for (int i = 0; i < 32; ++i) {
        const int idx = i * 256 + t;
        tile[idx >> 7][idx & 127] = W[(size_t)(k0 + (idx >> 7)) * D_ + (idx & 127)];
    }
    __syncthreads();
    const int n = t >> 1, hf = t & 1;
#pragma unroll
    for (int j = 0; j < 4; ++j) {
        const int kk = hf * 32 + j * 8;
        h8 hv;
#pragma unroll
        for (int e = 0; e < 8; ++e) hv[e] = (_Float16)tile[kk + e][n];
        *(h8*)&Wh[(size_t)(y * 128 + n) * E_ + k0 + kk] = hv;
    }
}

// =============== Kernel 1: fused QKV projection, fully double-buffered ===============
// grid = 256 = exactly 1 block/CU -> 112 KB LDS is free. One barrier per k-step:
// issue x(t+1)->regs and B(t+1)->Bs[c^1] BEFORE MFMA(t); MFMA covers B latency;
// vmcnt(12) releases x, vmcnt(0)+lgkm only at the barrier (B long landed).
__global__ __launch_bounds__(256, 1) void qkv_fused(
    const float* __restrict__ x, const _Float16* __restrict__ Wh,
    const float* __restrict__ bq, const float* __restrict__ bk,
    const float* __restrict__ bv,
    _Float16* __restrict__ Qh, _Float16* __restrict__ Kh,
    _Float16* __restrict__ Vt)
{
    __shared__ _Float16 As[2][64 * 64];     // 16 KB
    __shared__ _Float16 Bs[2][384 * 64];    // 96 KB

    const int t = threadIdx.x;
    const int lane = t & 63, w = t >> 6;
    const int quad = lane >> 4, col = lane & 15;
    const int m0 = blockIdx.x * 64;

    f4 acc[4][6];
#pragma unroll
    for (int mt = 0; mt < 4; ++mt)
#pragma unroll
        for (int nt = 0; nt < 6; ++nt) acc[mt][nt] = (f4){0.f, 0.f, 0.f, 0.f};

    const int brl = lane >> 3, bc = lane & 7;       // W-stage: 8 rows x 8 chunks
    const int xr_ = t >> 2, xcb = (t & 3) * 16;     // x-stage: row, col-base

    float4 xv[4];

#define LOAD_X(kb)                                                          \
    {   const float* xr = &x[(size_t)(m0 + xr_) * E_ + (kb) + xcb];         \
        _Pragma("unroll")                                                   \
        for (int i = 0; i < 4; ++i) xv[i] = *(const float4*)(xr + 4 * i);   }

#define STAGE_B(dst, kb)                                                    \
    _Pragma("unroll")                                                       \
    for (int i = 0; i < 12; ++i) {                                          \
        const int R = w * 96 + i * 8;                                       \
        const int r = R + brl;                                              \
        gl_lds16(Wh + (size_t)r * E_ + (kb) + 8 * (bc ^ (r & 7)), &(dst)[R * 64]); }

#define WRITE_A(dst)                                                        \
    _Pragma("unroll")                                                       \
    for (int i = 0; i < 4; ++i) {                                           \
        h4 hv; hv[0] = (_Float16)xv[i].x; hv[1] = (_Float16)xv[i].y;        \
        hv[2] = (_Float16)xv[i].z; hv[3] = (_Float16)xv[i].w;               \
        const int kk4 = xcb + 4 * i;                                        \
        *(h4*)&(dst)[xr_ * 64 + (((kk4 >> 3) ^ (xr_ & 7)) << 3) + (kk4 & 7)] = hv; }

    // ---- prologue: fill buffer 0 ----
    LOAD_X(0);                                          // 4 out (oldest)
    STAGE_B(Bs[0], 0);                                  // 16 out
    asm volatile("s_waitcnt vmcnt(12)" ::: "memory");   // x(0) landed
    WRITE_A(As[0]);
    asm volatile("s_waitcnt vmcnt(0) lgkmcnt(0)" ::: "memory");
    __builtin_amdgcn_s_barrier();

#pragma unroll 2
    for (int it = 0; it < 12; ++it) {
        const int c = it & 1;
        if (it < 11) {
            LOAD_X((it + 1) * 64);                      // 4 out (oldest)
            STAGE_B(Bs[c ^ 1], (it + 1) * 64);          // 16 out
        }
        // ---- MFMA on As[c], Bs[c] — covers the in-flight loads' latency ----
#pragma unroll
        for (int ks = 0; ks < 2; ++ks) {
            const int sc = ((ks << 2) + quad) ^ (col & 7);
            h8 a[4], bf[6];
#pragma unroll
            for (int mt = 0; mt < 4; ++mt)
                a[mt] = *(const h8*)&As[c][(mt * 16 + col) * 64 + (sc << 3)];
#pragma unroll
            for (int nt = 0; nt < 6; ++nt)
                bf[nt] = *(const h8*)&Bs[c][(w * 96 + nt * 16 + col) * 64 + (sc << 3)];
#pragma unroll
            for (int mt = 0; mt < 4; ++mt)
#pragma unroll
                for (int nt = 0; nt < 6; ++nt)
                    acc[mt][nt] = __builtin_amdgcn_mfma_f32_16x16x32_f16(
                        a[mt], bf[nt], acc[mt][nt], 0, 0, 0);
        }
        if (it < 11) {
            asm volatile("s_waitcnt vmcnt(12)" ::: "memory");   // x regs ready
            WRITE_A(As[c ^ 1]);
            asm volatile("s_waitcnt vmcnt(0) lgkmcnt(0)" ::: "memory");
            __builtin_amdgcn_s_barrier();
        }
    }

    // ---- epilogue: bias add into LDS (Cs[64][384] = Bs[0]), coalesced out ----
    // (last iter reads Bs[1]; Cs = Bs[0] region is disjoint, so no extra barrier)
    const float* bp[3] = {bq, bk, bv};
    _Float16* Cs = &Bs[0][0];
#pragma unroll
    for (int nt = 0; nt < 6; ++nt) {
        const int n16 = w * 96 + nt * 16;
        const int y = n16 >> 7, nl = n16 & 127;
        const float bb = bp[y][nl + col];
#pragma unroll
        for (int mt = 0; mt < 4; ++mt)
#pragma unroll
            for (int reg = 0; reg < 4; ++reg) {
                const int m = mt * 16 + quad * 4 + reg;
                Cs[m * 384 + n16 + col] = (_Float16)(acc[mt][nt][reg] + bb);
            }
    }
    __syncthreads();

    {   // Q/K rows: coalesced h8 stores
        const int m = t >> 2, seg = t & 3;
#pragma unroll
        for (int j = 0; j < 8; ++j) {
            const int n = seg * 64 + j * 8;
            const h8 v = *(const h8*)&Cs[m * 384 + n];
            if (n < 128) *(h8*)&Qh[(size_t)(m0 + m) * D_ + n] = v;
            else         *(h8*)&Kh[(size_t)(m0 + m) * D_ + (n - 128)] = v;
        }
    }
    {   // V transposed: [b][d][t]
        const int vn = t & 127, part = t >> 7;
        const int bidx = m0 >> 11, tt0 = m0 & 2047;
#pragma unroll
        for (int j = 0; j < 4; ++j) {
            const int ms = part * 32 + j * 8;
            h8 hv;
#pragma unroll
            for (int e = 0; e < 8; ++e) hv[e] = Cs[(ms + e) * 384 + 256 + vn];
            *(h8*)&Vt[((size_t)bidx * D_ + vn) * T_ + tt0 + ms] = hv;
        }
    }
#undef LOAD_X
#undef STAGE_B
#undef WRITE_A
}

// =============== Kernel 2: flash attention, swapped-QK^T in-register softmax ===============
// Zig-zag CU pairing: blocks id and id+256 co-reside (512 blocks, 2/CU); first 256
// get heavy diagonals (j32=63-k), second 256 the matching light ones (j32=k-32)
// -> per-CU total work ~constant (33.5 tile-steps) instead of 49 worst-case.
__global__ __launch_bounds__(256, 2) void flash_attn(
    const _Float16* __restrict__ Qh,
    const _Float16* __restrict__ Kh,
    const _Float16* __restrict__ Vt,
    float* __restrict__ out)
{
    __shared__ __align__(16) char smem[70656];
    _Float16* Ks = (_Float16*)smem;                    // [2][64 key][128 d]  32 KB
    _Float16* Vs = (_Float16*)(smem + 32768);          // [2][128 d][64 t]    32 KB
    _Float16* Pb = (_Float16*)(smem + 65536);          // [4][16 q][40 key]    5 KB

    const int t = threadIdx.x, lane = t & 63, w = t >> 6;
    const int quad = lane >> 4, col = lane & 15;
    const int id = blockIdx.x;
    const int b = id & 7;
    const int k6 = id >> 3;
    const int j32 = (k6 < 32) ? (63 - k6) : (k6 - 32);   // zig-zag heavy/light pairing
    const int qw = w & 1, kh = w >> 1;
    const int qbase = j32 * 32;
    const int qrow0 = qbase + qw * 16;
    const int nk = (j32 >> 1) + 1;

    h8 qf[4];
    const _Float16* Qp = Qh + ((size_t)b * T_ + qrow0 + col) * D_ + quad * 8;
#pragma unroll
    for (int ks = 0; ks < 4; ++ks) qf[ks] = *(const h8*)(Qp + ks * 32);
    asm volatile("s_waitcnt vmcnt(0)" ::: "memory");   // keep vmcnt clean for counting

    f4 o[8];
#pragma unroll
    for (int i = 0; i < 8; ++i) o[i] = (f4){0.f, 0.f, 0.f, 0.f};
    float m_st = -1e30f, l_st = 0.f;

    const _Float16* Kb = Kh + (size_t)b * T_ * D_;
    const _Float16* Vb = Vt + (size_t)b * D_ * T_;
    const int krl = lane >> 4, kc = lane & 15;
    const int vrl = lane >> 3, vc = lane & 7;
    const int cx = col & 7;

    auto stage = [&](int buf, int kbase) __attribute__((always_inline)) {
        _Float16* KsB = Ks + buf * 8192;
        _Float16* VsB = Vs + buf * 8192;
#pragma unroll
        for (int i = 0; i < 4; ++i) {
            const int R = w * 16 + i * 4;
            const int r = R + krl;
            gl_lds16(Kb + (size_t)(kbase + r) * D_ + 8 * (kc ^ (r & 7)), KsB + R * D_);
        }
#pragma unroll
        for (int i = 0; i < 4; ++i) {
            const int R = w * 32 + i * 8;
            const int d = R + vrl;
            gl_lds16(Vb + (size_t)d * T_ + kbase + 8 * (vc ^ (d & 7)), VsB + R * 64);
        }
    };

    _Float16* Pw = Pb + w * 640;   // [16 q][40 key-pad] per wave

    auto step = [&](int ti, int buf, bool mask) __attribute__((always_inline)) {
        const _Float16* KsB = Ks + buf * 8192;
        const _Float16* VsB = Vs + buf * 8192;

        // ---- QK^T swapped: s^T[key][q], lane: q=col, keys nt*16+quad*4+reg ----
        f4 s[2];
        s[0] = (f4){0.f, 0.f, 0.f, 0.f};
        s[1] = (f4){0.f, 0.f, 0.f, 0.f};
        __builtin_amdgcn_s_setprio(1);
#pragma unroll
        for (int nt = 0; nt < 2; ++nt) {
            const int r = kh * 32 + nt * 16 + col;
#pragma unroll
            for (int ks = 0; ks < 4; ++ks) {
                const h8 kf = *(const h8*)(KsB + r * D_ + 8 * (((ks << 2) + quad) ^ cx));
                s[nt] = __builtin_amdgcn_mfma_f32_16x16x32_f16(kf, qf[ks], s[nt], 0, 0, 0);
            }
        }
        __builtin_amdgcn_s_setprio(0);

        const int qr = qrow0 + col;
        if (mask) {
#pragma unroll
            for (int nt = 0; nt < 2; ++nt) {
                const int key = ti * 64 + kh * 32 + nt * 16 + quad * 4;
#pragma unroll
                for (int reg = 0; reg < 4; ++reg) {
                    const float sv = s[nt][reg] * SCALE2;
                    s[nt][reg] = (key + reg <= qr) ? sv : -1e30f;
                }
            }
        } else {
#pragma unroll
            for (int nt = 0; nt < 2; ++nt)
#pragma unroll
                for (int reg = 0; reg < 4; ++reg) s[nt][reg] *= SCALE2;
        }

        // ---- row max: 7 in-reg + 2 shfl rounds (quad combine) ----
        float mloc = fmaxf(fmaxf(fmaxf(s[0][0], s[0][1]), fmaxf(s[0][2], s[0][3])),
                           fmaxf(fmaxf(s[1][0], s[1][1]), fmaxf(s[1][2], s[1][3])));
        mloc = fmaxf(mloc, __shfl_xor(mloc, 16));
        mloc = fmaxf(mloc, __shfl_xor(mloc, 32));

        // ---- defer-max rescale ----
        if (__any((int)(mloc > m_st))) {
            const float mn = fmaxf(m_st, mloc);
            const float al = __builtin_amdgcn_exp2f(m_st - mn);
            m_st = mn;
            l_st *= al;
#pragma unroll
            for (int n2 = 0; n2 < 8; ++n2) o[n2] *= al;
        }

        float rs = 0.f;
#pragma unroll
        for (int nt = 0; nt < 2; ++nt)
#pragma unroll
            for (int reg = 0; reg < 4; ++reg) {
                const float p = __builtin_amdgcn_exp2f(s[nt][reg] - m_st);
                s[nt][reg] = p;
                rs += p;
            }
        rs += __shfl_xor(rs, 16);
        rs += __shfl_xor(rs, 32);
        l_st += rs;

        // ---- P^T -> B-frag relayout: 4 packed h2 writes + 1 b128 read ----
#pragma unroll
        for (int nt = 0; nt < 2; ++nt) {
            h2 p0; p0[0] = (_Float16)s[nt][0]; p0[1] = (_Float16)s[nt][1];
            h2 p1; p1[0] = (_Float16)s[nt][2]; p1[1] = (_Float16)s[nt][3];
            *(h2*)&Pw[col * 40 + nt * 16 + quad * 4]     = p0;
            *(h2*)&Pw[col * 40 + nt * 16 + quad * 4 + 2] = p1;
        }
        const h8 pa = *(const h8*)&Pw[col * 40 + quad * 8];

        // ---- PV: O^T[d][q] += V^T[d][k] P^T[k][q] ----
        __builtin_amdgcn_s_setprio(1);
#pragma unroll
        for (int n2 = 0; n2 < 8; ++n2) {
            const int d = n2 * 16 + col;
            const h8 vf = *(const h8*)(VsB + d * 64 + 8 * ((kh * 4 + quad) ^ (d & 7)));
            o[n2] = __builtin_amdgcn_mfma_f32_16x16x32_f16(vf, pa, o[n2], 0, 0, 0);
        }
        __builtin_amdgcn_s_setprio(0);
    };

    // ---- main loop: counted vmcnt, raw barriers ----
    stage(0, 0);
    const bool evenJ = ((j32 & 1) == 0);
    for (int ti = 0; ti < nk; ++ti) {
        const int cur = ti & 1;
        if (ti + 1 < nk) {
            stage(cur ^ 1, (ti + 1) << 6);
            asm volatile("s_waitcnt vmcnt(8)" ::: "memory");   // tile ti landed
        } else {
            asm volatile("s_waitcnt vmcnt(0)" ::: "memory");
        }
        __builtin_amdgcn_s_barrier();
        const bool last = (ti == nk - 1);
        if (!(last && evenJ && kh == 1)) {
            const bool mask = last && (kh == (j32 & 1));
            step(ti, cur, mask);
        }
        __builtin_amdgcn_s_barrier();
    }

    // ---- merge kh halves in O^T space, then coalesced store ----
    float* Os = (float*)smem;              // [32 q][132 d] f32 (16.9 KB, Ks area)
    float* Mx = (float*)(smem + 16896);    // [32]
    float* Lx = Mx + 32;                   // [32]
    const int qloc = qw * 16 + col;

    __syncthreads();
    if (kh == 1) {
        if (quad == 0) { Mx[qloc] = m_st; Lx[qloc] = l_st; }
#pragma unroll
        for (int n2 = 0; n2 < 8; ++n2)
#pragma unroll
            for (int reg = 0; reg < 4; ++reg)
                Os[qloc * 132 + n2 * 16 + quad * 4 + reg] = o[n2][reg];
    }
    __syncthreads();
    if (kh == 0) {
        const float m1 = Mx[qloc], l1 = Lx[qloc];
        const float mN = fmaxf(m_st, m1);
        const float a0 = __builtin_amdgcn_exp2f(m_st - mN);
        const float a1 = __builtin_amdgcn_exp2f(m1 - mN);
        const float inv = 1.0f / (l_st * a0 + l1 * a1);
#pragma unroll
        for (int n2 = 0; n2 < 8; ++n2)
#pragma unroll
            for (int reg = 0; reg < 4; ++reg) {
                const int d = n2 * 16 + quad * 4 + reg;
                Os[qloc * 132 + d] = (o[n2][reg] * a0 + Os[qloc * 132 + d] * a1) * inv;
            }
    }
    __syncthreads();
    {   // coalesced f32 store
        const int row = t >> 3, d0 = (t & 7) * 16;
        float* op = &out[((size_t)b * T_ + qbase + row) * D_ + d0];
#pragma unroll
        for (int j = 0; j < 4; ++j)
            *(float4*)(op + j * 4) = *(const float4*)&Os[row * 132 + d0 + j * 4];
    }
}

extern "C" void kernel_launch(void* const* d_in, const int* in_sizes, int n_in,
                              void* d_out, int out_size, void* d_ws, size_t ws_size,
                              hipStream_t stream) {
    const float* x  = (const float*)d_in[0];
    const float* Wq = (const float*)d_in[1];
    const float* bq = (const float*)d_in[2];
    const float* Wk = (const float*)d_in[3];
    const float* bk = (const float*)d_in[4];
    const float* Wv = (const float*)d_in[5];
    const float* bv = (const float*)d_in[6];

    _Float16* Qh = (_Float16*)d_ws;                       // [B*T][D] f16
    _Float16* Kh = Qh + (size_t)B_ * T_ * D_;             // [B*T][D] f16
    _Float16* Vt = Kh + (size_t)B_ * T_ * D_;             // [B][D][T] f16
    _Float16* Wh = (_Float16*)d_out;                      // [3*128][768] f16 (scratch)

    w_prep<<<dim3(36), dim3(256), 0, stream>>>(Wq, Wk, Wv, Wh);
    qkv_fused<<<dim3(B_ * T_ / 64), dim3(256), 0, stream>>>(
        x, Wh, bq, bk, bv, Qh, Kh, Vt);
    flash_attn<<<dim3(512), dim3(256), 0, stream>>>(Qh, Kh, Vt, (float*)d_out);
}

// Round 5
// 150.732 us; speedup vs baseline: 1.9592x; 1.0151x over previous
//
#include <hip/hip_runtime.h>

#define B_ 8
#define T_ 2048
#define E_ 768
#define D_ 128
// scores kept in exp2 domain: scale = (1/sqrt(128)) * log2(e)
#define SCALE2 (0.08838834764831845f * 1.4426950408889634f)

typedef _Float16 h8 __attribute__((ext_vector_type(8)));
typedef _Float16 h4 __attribute__((ext_vector_type(4)));
typedef _Float16 h2 __attribute__((ext_vector_type(2)));
typedef float f4 __attribute__((ext_vector_type(4)));

typedef __attribute__((address_space(1))) unsigned int as1_u32;
typedef __attribute__((address_space(3))) unsigned int as3_u32;

__device__ __forceinline__ void gl_lds16(const void* g, void* l) {
    __builtin_amdgcn_global_load_lds((const as1_u32*)g, (as3_u32*)l, 16, 0, 0);
}

// =============== Kernel 0: W (fp32 [768][128] x3) -> Wh f16 [3*128][768] ===============
__global__ __launch_bounds__(256) void w_prep(
    const float* __restrict__ Wq, const float* __restrict__ Wk,
    const float* __restrict__ Wv, _Float16* __restrict__ Wh)
{
    __shared__ float tile[64][129];
    const int y = blockIdx.x / 12, kc = blockIdx.x % 12;
    const float* W = (y == 0) ? Wq : (y == 1) ? Wk : Wv;
    const int k0 = kc * 64, t = threadIdx.x;
#pragma unroll
    for (int i = 0; i < 32; ++i) {
        const int idx = i * 256 + t;
        tile[idx >> 7][idx & 127] = W[(size_t)(k0 + (idx >> 7)) * D_ + (idx & 127)];
    }
    __syncthreads();
    const int n = t >> 1, hf = t & 1;
#pragma unroll
    for (int j = 0; j < 4; ++j) {
        const int kk = hf * 32 + j * 8;
        h8 hv;
#pragma unroll
        for (int e = 0; e < 8; ++e) hv[e] = (_Float16)tile[kk + e][n];
        *(h8*)&Wh[(size_t)(y * 128 + n) * E_ + k0 + kk] = hv;
    }
}

// =============== Kernel 1: fused QKV projection, 8 waves (2/SIMD) ===============
// grid = 256 (64-row m-tile), block = 512: each wave owns 48 of 384 cols.
// 2 waves/SIMD -> MFMA of one wave covers the other's LDS-read/barrier stalls.
// Double-buffered As/Bs (112 KB LDS); loads for t+1 issued before MFMA(t).
__global__ __launch_bounds__(512, 1) void qkv_fused(
    const float* __restrict__ x, const _Float16* __restrict__ Wh,
    const float* __restrict__ bq, const float* __restrict__ bk,
    const float* __restrict__ bv,
    _Float16* __restrict__ Qh, _Float16* __restrict__ Kh,
    _Float16* __restrict__ Vt)
{
    __shared__ _Float16 As[2][64 * 64];     // 16 KB
    __shared__ _Float16 Bs[2][384 * 64];    // 96 KB

    const int t = threadIdx.x;
    const int lane = t & 63, w = t >> 6;            // w = 0..7
    const int quad = lane >> 4, col = lane & 15;
    const int m0 = blockIdx.x * 64;

    f4 acc[4][3];
#pragma unroll
    for (int mt = 0; mt < 4; ++mt)
#pragma unroll
        for (int nt = 0; nt < 3; ++nt) acc[mt][nt] = (f4){0.f, 0.f, 0.f, 0.f};

    const int brl = lane >> 3, bc = lane & 7;       // W-stage: 8 rows x 8 chunks
    const int xr_ = t >> 3, xcb = (t & 7) * 8;      // x-stage: row, col-base (8 floats)

    float4 xv[2];

#define LOAD_X(kb)                                                          \
    {   const float* xr = &x[(size_t)(m0 + xr_) * E_ + (kb) + xcb];         \
        xv[0] = *(const float4*)(xr);                                       \
        xv[1] = *(const float4*)(xr + 4);                                   }

#define STAGE_B(dst, kb)                                                    \
    _Pragma("unroll")                                                       \
    for (int i = 0; i < 6; ++i) {                                           \
        const int R = w * 48 + i * 8;                                       \
        const int r = R + brl;                                              \
        gl_lds16(Wh + (size_t)r * E_ + (kb) + 8 * (bc ^ (r & 7)), &(dst)[R * 64]); }

#define WRITE_A(dst)                                                        \
    _Pragma("unroll")                                                       \
    for (int i = 0; i < 2; ++i) {                                           \
        h4 hv; hv[0] = (_Float16)xv[i].x; hv[1] = (_Float16)xv[i].y;        \
        hv[2] = (_Float16)xv[i].z; hv[3] = (_Float16)xv[i].w;               \
        const int kk4 = xcb + 4 * i;                                        \
        *(h4*)&(dst)[xr_ * 64 + (((kk4 >> 3) ^ (xr_ & 7)) << 3) + (kk4 & 7)] = hv; }

    // ---- prologue: fill buffer 0 ----
    LOAD_X(0);                                      // 2 out (oldest)
    STAGE_B(Bs[0], 0);                              // 6 out
    asm volatile("s_waitcnt vmcnt(6)" ::: "memory"); // x(0) landed
    WRITE_A(As[0]);
    asm volatile("s_waitcnt vmcnt(0) lgkmcnt(0)" ::: "memory");
    __builtin_amdgcn_s_barrier();

#pragma unroll 2
    for (int it = 0; it < 12; ++it) {
        const int c = it & 1;
        if (it < 11) {
            LOAD_X((it + 1) * 64);                  // 2 out (oldest)
            STAGE_B(Bs[c ^ 1], (it + 1) * 64);      // 6 out
        }
        // ---- MFMA on As[c], Bs[c] — covers the in-flight loads' latency ----
#pragma unroll
        for (int ks = 0; ks < 2; ++ks) {
            const int sc = ((ks << 2) + quad) ^ (col & 7);
            h8 a[4], bf[3];
#pragma unroll
            for (int mt = 0; mt < 4; ++mt)
                a[mt] = *(const h8*)&As[c][(mt * 16 + col) * 64 + (sc << 3)];
#pragma unroll
            for (int nt = 0; nt < 3; ++nt)
                bf[nt] = *(const h8*)&Bs[c][(w * 48 + nt * 16 + col) * 64 + (sc << 3)];
#pragma unroll
            for (int mt = 0; mt < 4; ++mt)
#pragma unroll
                for (int nt = 0; nt < 3; ++nt)
                    acc[mt][nt] = __builtin_amdgcn_mfma_f32_16x16x32_f16(
                        a[mt], bf[nt], acc[mt][nt], 0, 0, 0);
        }
        if (it < 11) {
            asm volatile("s_waitcnt vmcnt(6)" ::: "memory");    // x regs ready
            WRITE_A(As[c ^ 1]);
            asm volatile("s_waitcnt vmcnt(0) lgkmcnt(0)" ::: "memory");
            __builtin_amdgcn_s_barrier();
        }
    }

    // ---- epilogue: bias add into LDS (Cs[64][384] = Bs[0]), coalesced out ----
    // (last iter reads Bs[1]/As[1]; Cs = Bs[0] region is disjoint)
    const float* bp[3] = {bq, bk, bv};
    _Float16* Cs = &Bs[0][0];
#pragma unroll
    for (int nt = 0; nt < 3; ++nt) {
        const int n16 = w * 48 + nt * 16;
        const int y = n16 >> 7, nl = n16 & 127;
        const float bb = bp[y][nl + col];
#pragma unroll
        for (int mt = 0; mt < 4; ++mt)
#pragma unroll
            for (int reg = 0; reg < 4; ++reg) {
                const int m = mt * 16 + quad * 4 + reg;
                Cs[m * 384 + n16 + col] = (_Float16)(acc[mt][nt][reg] + bb);
            }
    }
    __syncthreads();

    {   // Q/K rows: coalesced h8 stores (512 threads: 4 chunks each)
        const int m = t >> 3, seg = t & 7;
#pragma unroll
        for (int j = 0; j < 4; ++j) {
            const int n = seg * 8 + j * 64;
            const h8 v = *(const h8*)&Cs[m * 384 + n];
            if (n < 128) *(h8*)&Qh[(size_t)(m0 + m) * D_ + n] = v;
            else         *(h8*)&Kh[(size_t)(m0 + m) * D_ + (n - 128)] = v;
        }
    }
    {   // V transposed: [b][d][t] (512 threads: 2 gathers each)
        const int vn = t & 127, part = t >> 7;
        const int bidx = m0 >> 11, tt0 = m0 & 2047;
#pragma unroll
        for (int j = 0; j < 2; ++j) {
            const int ms = part * 16 + j * 8;
            h8 hv;
#pragma unroll
            for (int e = 0; e < 8; ++e) hv[e] = Cs[(ms + e) * 384 + 256 + vn];
            *(h8*)&Vt[((size_t)bidx * D_ + vn) * T_ + tt0 + ms] = hv;
        }
    }
#undef LOAD_X
#undef STAGE_B
#undef WRITE_A
}

// =============== Kernel 2: flash attention, swapped-QK^T in-register softmax ===============
// Zig-zag CU pairing: blocks id and id+256 co-reside (512 blocks, 2/CU); first 256
// get heavy diagonals (j32=63-k), second 256 the matching light ones (j32=k-32)
// -> per-CU total work ~constant (33.5 tile-steps) instead of 49 worst-case.
__global__ __launch_bounds__(256, 2) void flash_attn(
    const _Float16* __restrict__ Qh,
    const _Float16* __restrict__ Kh,
    const _Float16* __restrict__ Vt,
    float* __restrict__ out)
{
    __shared__ __align__(16) char smem[70656];
    _Float16* Ks = (_Float16*)smem;                    // [2][64 key][128 d]  32 KB
    _Float16* Vs = (_Float16*)(smem + 32768);          // [2][128 d][64 t]    32 KB
    _Float16* Pb = (_Float16*)(smem + 65536);          // [4][16 q][40 key]    5 KB

    const int t = threadIdx.x, lane = t & 63, w = t >> 6;
    const int quad = lane >> 4, col = lane & 15;
    const int id = blockIdx.x;
    const int b = id & 7;
    const int k6 = id >> 3;
    const int j32 = (k6 < 32) ? (63 - k6) : (k6 - 32);   // zig-zag heavy/light pairing
    const int qw = w & 1, kh = w >> 1;
    const int qbase = j32 * 32;
    const int qrow0 = qbase + qw * 16;
    const int nk = (j32 >> 1) + 1;

    h8 qf[4];
    const _Float16* Qp = Qh + ((size_t)b * T_ + qrow0 + col) * D_ + quad * 8;
#pragma unroll
    for (int ks = 0; ks < 4; ++ks) qf[ks] = *(const h8*)(Qp + ks * 32);
    asm volatile("s_waitcnt vmcnt(0)" ::: "memory");   // keep vmcnt clean for counting

    f4 o[8];
#pragma unroll
    for (int i = 0; i < 8; ++i) o[i] = (f4){0.f, 0.f, 0.f, 0.f};
    float m_st = -1e30f, l_st = 0.f;

    const _Float16* Kb = Kh + (size_t)b * T_ * D_;
    const _Float16* Vb = Vt + (size_t)b * D_ * T_;
    const int krl = lane >> 4, kc = lane & 15;
    const int vrl = lane >> 3, vc = lane & 7;
    const int cx = col & 7;

    auto stage = [&](int buf, int kbase) __attribute__((always_inline)) {
        _Float16* KsB = Ks + buf * 8192;
        _Float16* VsB = Vs + buf * 8192;
#pragma unroll
        for (int i = 0; i < 4; ++i) {
            const int R = w * 16 + i * 4;
            const int r = R + krl;
            gl_lds16(Kb + (size_t)(kbase + r) * D_ + 8 * (kc ^ (r & 7)), KsB + R * D_);
        }
#pragma unroll
        for (int i = 0; i < 4; ++i) {
            const int R = w * 32 + i * 8;
            const int d = R + vrl;
            gl_lds16(Vb + (size_t)d * T_ + kbase + 8 * (vc ^ (d & 7)), VsB + R * 64);
        }
    };

    _Float16* Pw = Pb + w * 640;   // [16 q][40 key-pad] per wave

    auto step = [&](int ti, int buf, bool mask) __attribute__((always_inline)) {
        const _Float16* KsB = Ks + buf * 8192;
        const _Float16* VsB = Vs + buf * 8192;

        // ---- QK^T swapped: s^T[key][q], lane: q=col, keys nt*16+quad*4+reg ----
        f4 s[2];
        s[0] = (f4){0.f, 0.f, 0.f, 0.f};
        s[1] = (f4){0.f, 0.f, 0.f, 0.f};
        __builtin_amdgcn_s_setprio(1);
#pragma unroll
        for (int nt = 0; nt < 2; ++nt) {
            const int r = kh * 32 + nt * 16 + col;
#pragma unroll
            for (int ks = 0; ks < 4; ++ks) {
                const h8 kf = *(const h8*)(KsB + r * D_ + 8 * (((ks << 2) + quad) ^ cx));
                s[nt] = __builtin_amdgcn_mfma_f32_16x16x32_f16(kf, qf[ks], s[nt], 0, 0, 0);
            }
        }
        __builtin_amdgcn_s_setprio(0);

        const int qr = qrow0 + col;
        if (mask) {
#pragma unroll
            for (int nt = 0; nt < 2; ++nt) {
                const int key = ti * 64 + kh * 32 + nt * 16 + quad * 4;
#pragma unroll
                for (int reg = 0; reg < 4; ++reg) {
                    const float sv = s[nt][reg] * SCALE2;
                    s[nt][reg] = (key + reg <= qr) ? sv : -1e30f;
                }
            }
        } else {
#pragma unroll
            for (int nt = 0; nt < 2; ++nt)
#pragma unroll
                for (int reg = 0; reg < 4; ++reg) s[nt][reg] *= SCALE2;
        }

        // ---- row max: 7 in-reg + 2 shfl rounds (quad combine) ----
        float mloc = fmaxf(fmaxf(fmaxf(s[0][0], s[0][1]), fmaxf(s[0][2], s[0][3])),
                           fmaxf(fmaxf(s[1][0], s[1][1]), fmaxf(s[1][2], s[1][3])));
        mloc = fmaxf(mloc, __shfl_xor(mloc, 16));
        mloc = fmaxf(mloc, __shfl_xor(mloc, 32));

        // ---- defer-max rescale ----
        if (__any((int)(mloc > m_st))) {
            const float mn = fmaxf(m_st, mloc);
            const float al = __builtin_amdgcn_exp2f(m_st - mn);
            m_st = mn;
            l_st *= al;
#pragma unroll
            for (int n2 = 0; n2 < 8; ++n2) o[n2] *= al;
        }

        float rs = 0.f;
#pragma unroll
        for (int nt = 0; nt < 2; ++nt)
#pragma unroll
            for (int reg = 0; reg < 4; ++reg) {
                const float p = __builtin_amdgcn_exp2f(s[nt][reg] - m_st);
                s[nt][reg] = p;
                rs += p;
            }
        rs += __shfl_xor(rs, 16);
        rs += __shfl_xor(rs, 32);
        l_st += rs;

        // ---- P^T -> B-frag relayout: 4 packed h2 writes + 1 b128 read ----
#pragma unroll
        for (int nt = 0; nt < 2; ++nt) {
            h2 p0; p0[0] = (_Float16)s[nt][0]; p0[1] = (_Float16)s[nt][1];
            h2 p1; p1[0] = (_Float16)s[nt][2]; p1[1] = (_Float16)s[nt][3];
            *(h2*)&Pw[col * 40 + nt * 16 + quad * 4]     = p0;
            *(h2*)&Pw[col * 40 + nt * 16 + quad * 4 + 2] = p1;
        }
        const h8 pa = *(const h8*)&Pw[col * 40 + quad * 8];

        // ---- PV: O^T[d][q] += V^T[d][k] P^T[k][q] ----
        __builtin_amdgcn_s_setprio(1);
#pragma unroll
        for (int n2 = 0; n2 < 8; ++n2) {
            const int d = n2 * 16 + col;
            const h8 vf = *(const h8*)(VsB + d * 64 + 8 * ((kh * 4 + quad) ^ (d & 7)));
            o[n2] = __builtin_amdgcn_mfma_f32_16x16x32_f16(vf, pa, o[n2], 0, 0, 0);
        }
        __builtin_amdgcn_s_setprio(0);
    };

    // ---- main loop: counted vmcnt, raw barriers ----
    stage(0, 0);
    const bool evenJ = ((j32 & 1) == 0);
    for (int ti = 0; ti < nk; ++ti) {
        const int cur = ti & 1;
        if (ti + 1 < nk) {
            stage(cur ^ 1, (ti + 1) << 6);
            asm volatile("s_waitcnt vmcnt(8)" ::: "memory");   // tile ti landed
        } else {
            asm volatile("s_waitcnt vmcnt(0)" ::: "memory");
        }
        __builtin_amdgcn_s_barrier();
        const bool last = (ti == nk - 1);
        if (!(last && evenJ && kh == 1)) {
            const bool mask = last && (kh == (j32 & 1));
            step(ti, cur, mask);
        }
        __builtin_amdgcn_s_barrier();
    }

    // ---- merge kh halves in O^T space, then coalesced store ----
    float* Os = (float*)smem;              // [32 q][132 d] f32 (16.9 KB, Ks area)
    float* Mx = (float*)(smem + 16896);    // [32]
    float* Lx = Mx + 32;                   // [32]
    const int qloc = qw * 16 + col;

    __syncthreads();
    if (kh == 1) {
        if (quad == 0) { Mx[qloc] = m_st; Lx[qloc] = l_st; }
#pragma unroll
        for (int n2 = 0; n2 < 8; ++n2)
#pragma unroll
            for (int reg = 0; reg < 4; ++reg)
                Os[qloc * 132 + n2 * 16 + quad * 4 + reg] = o[n2][reg];
    }
    __syncthreads();
    if (kh == 0) {
        const float m1 = Mx[qloc], l1 = Lx[qloc];
        const float mN = fmaxf(m_st, m1);
        const float a0 = __builtin_amdgcn_exp2f(m_st - mN);
        const float a1 = __builtin_amdgcn_exp2f(m1 - mN);
        const float inv = 1.0f / (l_st * a0 + l1 * a1);
#pragma unroll
        for (int n2 = 0; n2 < 8; ++n2)
#pragma unroll
            for (int reg = 0; reg < 4; ++reg) {
                const int d = n2 * 16 + quad * 4 + reg;
                Os[qloc * 132 + d] = (o[n2][reg] * a0 + Os[qloc * 132 + d] * a1) * inv;
            }
    }
    __syncthreads();
    {   // coalesced f32 store
        const int row = t >> 3, d0 = (t & 7) * 16;
        float* op = &out[((size_t)b * T_ + qbase + row) * D_ + d0];
#pragma unroll
        for (int j = 0; j < 4; ++j)
            *(float4*)(op + j * 4) = *(const float4*)&Os[row * 132 + d0 + j * 4];
    }
}

extern "C" void kernel_launch(void* const* d_in, const int* in_sizes, int n_in,
                              void* d_out, int out_size, void* d_ws, size_t ws_size,
                              hipStream_t stream) {
    const float* x  = (const float*)d_in[0];
    const float* Wq = (const float*)d_in[1];
    const float* bq = (const float*)d_in[2];
    const float* Wk = (const float*)d_in[3];
    const float* bk = (const float*)d_in[4];
    const float* Wv = (const float*)d_in[5];
    const float* bv = (const float*)d_in[6];

    _Float16* Qh = (_Float16*)d_ws;                       // [B*T][D] f16
    _Float16* Kh = Qh + (size_t)B_ * T_ * D_;             // [B*T][D] f16
    _Float16* Vt = Kh + (size_t)B_ * T_ * D_;             // [B][D][T] f16
    _Float16* Wh = (_Float16*)d_out;                      // [3*128][768] f16 (scratch)

    w_prep<<<dim3(36), dim3(256), 0, stream>>>(Wq, Wk, Wv, Wh);
    qkv_fused<<<dim3(B_ * T_ / 64), dim3(512), 0, stream>>>(
        x, Wh, bq, bk, bv, Qh, Kh, Vt);
    flash_attn<<<dim3(512), dim3(256), 0, stream>>>(Qh, Kh, Vt, (float*)d_out);
}